// Round 8
// baseline (456.892 us; speedup 1.0000x reference)
//
#include <hip/hip_runtime.h>
#include <math.h>

#define BB 4
#define CIN 64
#define CL 128     // 2*C_IN
#define DD 128     // projected dim
#define HW 4096
#define NN 4096
#define TP 132     // transpose lds pitch

typedef __attribute__((ext_vector_type(8))) __bf16 bf16x8;
typedef __attribute__((ext_vector_type(16))) float f32x16;

__device__ __forceinline__ unsigned short f2bf(float f) {
    unsigned u = __builtin_bit_cast(unsigned, f);
    u += 0x7fffu + ((u >> 16) & 1u);
    return (unsigned short)(u >> 16);
}
__device__ __forceinline__ unsigned pack2(float lo, float hi) {
    return (unsigned)f2bf(lo) | ((unsigned)f2bf(hi) << 16);
}
__device__ __forceinline__ float bf2f(unsigned s) {
    return __builtin_bit_cast(float, s << 16);
}
// truncating bf16 pair pack: 1 v_perm_b32 (P-operand only; bias <0.4%)
__device__ __forceinline__ unsigned pack_trunc(float lo, float hi) {
    return __builtin_amdgcn_perm(__builtin_bit_cast(unsigned, hi),
                                 __builtin_bit_cast(unsigned, lo), 0x07060302u);
}
__device__ __forceinline__ float exp2_fast(float x) {
#if __has_builtin(__builtin_amdgcn_exp2f)
    return __builtin_amdgcn_exp2f(x);
#else
    return __expf(x * 0.6931471805599453f);
#endif
}

// fp32-in projection, bf16 out, output scale. grid 512 = b*og(8)*chunk(16)
template<int CINT>
__global__ __launch_bounds__(256) void proj_kernel(
    const float* __restrict__ x, const float* __restrict__ w,
    const float* __restrict__ bias, unsigned short* __restrict__ out,
    float oscale)
{
    int blk = blockIdx.x;
    int chunk = blk & 15;
    int og = (blk >> 4) & 7;
    int b = blk >> 7;
    int o0 = og * 16;
    int hw = chunk * 256 + threadIdx.x;

    float acc[16];
#pragma unroll
    for (int oo = 0; oo < 16; ++oo) acc[oo] = bias[o0 + oo];
    const float* xb = x + (size_t)b * CINT * HW + hw;
    for (int c = 0; c < CINT; ++c) {
        float xv = xb[(size_t)c * HW];
#pragma unroll
        for (int oo = 0; oo < 16; ++oo)
            acc[oo] += xv * w[(o0 + oo) * CINT + c];
    }
#pragma unroll
    for (int oo = 0; oo < 16; ++oo)
        out[((size_t)b * 128 + o0 + oo) * HW + hw] = f2bf(acc[oo] * oscale);
}

// fused K+V projection (reads x_lower once). grid 512, 16 o x 256 px
__global__ __launch_bounds__(256) void proj_kv_kernel(
    const float* __restrict__ x,
    const float* __restrict__ wk, const float* __restrict__ bk,
    const float* __restrict__ wv, const float* __restrict__ bv,
    unsigned short* __restrict__ kout, unsigned short* __restrict__ vout)
{
    int blk = blockIdx.x;
    int chunk = blk & 15;
    int og = (blk >> 4) & 7;
    int b = blk >> 7;
    int o0 = og * 16;
    int hw = chunk * 256 + threadIdx.x;

    float ack[16], acv[16];
#pragma unroll
    for (int oo = 0; oo < 16; ++oo) { ack[oo] = bk[o0 + oo]; acv[oo] = bv[o0 + oo]; }
    const float* xb = x + (size_t)b * CL * HW + hw;
    for (int c = 0; c < CL; ++c) {
        float xv = xb[(size_t)c * HW];
#pragma unroll
        for (int oo = 0; oo < 16; ++oo) {
            ack[oo] += xv * wk[(o0 + oo) * CL + c];
            acv[oo] += xv * wv[(o0 + oo) * CL + c];
        }
    }
#pragma unroll
    for (int oo = 0; oo < 16; ++oo) {
        size_t oidx = ((size_t)b * 128 + o0 + oo) * HW + hw;
        kout[oidx] = f2bf(ack[oo]);
        vout[oidx] = f2bf(acv[oo]);
    }
}

// output projection: bf16 in, fp32 out with residual. grid 512, 16 o x 256 px
__global__ __launch_bounds__(256) void proj_o_kernel(
    const unsigned short* __restrict__ x, const float* __restrict__ w,
    const float* __restrict__ bias, const float* __restrict__ resid,
    float* __restrict__ out)
{
    int blk = blockIdx.x;
    int chunk = blk & 15;
    int og = (blk >> 4) & 7;
    int b = blk >> 7;
    int o0 = og * 16;
    int hw = chunk * 256 + threadIdx.x;

    float acc[16];
#pragma unroll
    for (int oo = 0; oo < 16; ++oo) acc[oo] = bias[o0 + oo];
    const unsigned short* xb = x + (size_t)b * DD * HW + hw;
    for (int c = 0; c < DD; ++c) {
        float xv = bf2f((unsigned)xb[(size_t)c * HW]);
#pragma unroll
        for (int oo = 0; oo < 16; ++oo)
            acc[oo] += xv * w[(o0 + oo) * DD + c];
    }
#pragma unroll
    for (int oo = 0; oo < 16; ++oo) {
        size_t oidx = ((size_t)b * 128 + o0 + oo) * HW + hw;
        out[oidx] = acc[oo] + resid[oidx];
    }
}

// bf16 [4096][128] -> [128][4096] per batch (attn-view transpose)
__global__ __launch_bounds__(256) void transpose_v(
    const unsigned short* __restrict__ vf, unsigned short* __restrict__ vt)
{
    __shared__ unsigned short tld[64 * TP];
    int tid = threadIdx.x;
    int b = blockIdx.x >> 6;
    int n0 = (blockIdx.x & 63) * 64;
    const unsigned short* src = vf + (size_t)b * NN * DD + (size_t)n0 * DD;
#pragma unroll
    for (int i = 0; i < 4; ++i) {
        int ch = tid + i * 256;
        int n = ch >> 4, x = ch & 15;
        union { uint4 q; unsigned long long u[2]; } t;
        t.q = *(const uint4*)(src + (size_t)n * DD + x * 8);
        unsigned short* d = &tld[n * TP + x * 8];
        *(unsigned long long*)(d) = t.u[0];
        *(unsigned long long*)(d + 4) = t.u[1];
    }
    __syncthreads();
    unsigned short* dst = vt + (size_t)b * NN * DD + n0;
#pragma unroll
    for (int i = 0; i < 4; ++i) {
        int ch = tid + i * 256;
        int g = ch & 7, d = ch >> 3;
        union { uint4 q; unsigned short s[8]; } t;
#pragma unroll
        for (int j = 0; j < 8; ++j) t.s[j] = tld[(g * 8 + j) * TP + d];
        *(uint4*)(dst + (size_t)d * NN + g * 8) = t.q;
    }
}

// MFMA flash attention v6: XOR-swizzled dense LDS tiles (conflict-free b128),
// S^T formulation, shfl-exchanged P. Register diet vs R7 (which spilled
// ~800MB to scratch): Q frags live in LDS (read JIT), staging addresses
// strength-reduced to 3 base regs + immediate offsets.
__global__ __launch_bounds__(256, 2) void attn_mfma(
    const unsigned short* __restrict__ qf, const unsigned short* __restrict__ kf,
    const unsigned short* __restrict__ vt, unsigned short* __restrict__ of)
{
    __shared__ __align__(16) char smem[74752];
    unsigned short* k_lds = (unsigned short*)smem;            // [128 key][128 d] swizzled
    unsigned short* v_lds = (unsigned short*)(smem + 32768);  // [128 d][128 key] swizzled
    unsigned short* q_lds = (unsigned short*)(smem + 66560);  // [32 q][128 d] swizzled
    float (*red_o)[32][129] = (float (*)[32][129])smem;       // aliased after K-loop
    float* red_l = (float*)(smem + 66048);                    // [4][32]

    const int tid = threadIdx.x;
    const int lane = tid & 63;
    const int w = tid >> 6;            // wave 0..3 : key quarter
    const int half = lane >> 5;
    const int l5 = lane & 31;
    const int b = blockIdx.x >> 7;
    const int rw0 = (blockIdx.x & 127) * 32;   // block's 32 q-rows
    const int cw = w * 32;             // wave's key quarter in 128-supertile

    const unsigned short* qb = qf + (size_t)b * NN * DD;
    const unsigned short* kb = kf + (size_t)b * NN * DD;
    const unsigned short* vb = vt + (size_t)b * NN * DD;   // [128 d][4096 n]

    // stage Q (32 x 128, swizzled like K) once; frags read JIT in the K-loop
    {
#pragma unroll
        for (int j = 0; j < 2; ++j) {
            int ck = tid + j * 256;            // 512 chunks of 16B
            int qr = ck >> 4, qx = ck & 15;
            uint4 qv = *(const uint4*)(qb + (size_t)(rw0 + qr) * DD + qx * 8);
            *(uint4*)&q_lds[qr * 128 + ((qx ^ (qr & 15)) * 8)] = qv;
        }
    }

    // staging geometry, affine in chunk index i (r = r0+16i, x = x0 const):
    const int r0 = tid >> 4;
    const int x0 = tid & 15;
    const int ro0 = r0 * 128 + ((x0 ^ (r0 & 15)) * 8);   // LDS elem offset base
    const unsigned short* kp = kb + (size_t)r0 * DD + x0 * 8;   // += 16384/tile
    const unsigned short* vp = vb + (size_t)r0 * NN + x0 * 8;   // += 128/tile

    uint4 kch[8], vch[8];
#pragma unroll
    for (int i = 0; i < 8; ++i) {      // preload supertile 0
        kch[i] = *(const uint4*)(kp + i * 2048);
        vch[i] = *(const uint4*)(vp + (size_t)i * 65536);
    }
    kp += 16384; vp += 128;

    f32x16 O[4] = {};
    float lacc = 0.f;

    for (int t = 0; t < NN / 128; ++t) {
        __syncthreads();               // previous tile's frag reads done
#pragma unroll
        for (int i = 0; i < 8; ++i) {
            *(uint4*)&k_lds[ro0 + i * 2048] = kch[i];
            *(uint4*)&v_lds[ro0 + i * 2048] = vch[i];
        }
        // prefetch tile t+1 (last-iter reads dangle inside ws, never committed)
#pragma unroll
        for (int i = 0; i < 8; ++i) {
            kch[i] = *(const uint4*)(kp + i * 2048);
            vch[i] = *(const uint4*)(vp + (size_t)i * 65536);
        }
        kp += 16384; vp += 128;
        __syncthreads();               // staged tile visible

        // S^T = K·Q^T : A lane = key cw+l5; B lane = q-row l5 (both deswizzled)
        f32x16 S = {};
#pragma unroll
        for (int kk = 0; kk < 8; ++kk) {
            bf16x8 kfr = *(const bf16x8*)
                &k_lds[(cw + l5) * 128 + (((kk * 2 + half) ^ (l5 & 15)) * 8)];
            bf16x8 qfr = *(const bf16x8*)
                &q_lds[l5 * 128 + (((kk * 2 + half) ^ (l5 & 15)) * 8)];
            S = __builtin_amdgcn_mfma_f32_32x32x16_bf16(kfr, qfr, S, 0, 0, 0);
        }

        // softmax numerator (no max subtraction: |S| < ~3 in log2 domain)
        float p[16];
#pragma unroll
        for (int r = 0; r < 16; ++r) p[r] = exp2_fast(S[r]);
        {
            float t0 = (p[0] + p[1]) + (p[2] + p[3]);
            float t1 = (p[4] + p[5]) + (p[6] + p[7]);
            float t2 = (p[8] + p[9]) + (p[10] + p[11]);
            float t3 = (p[12] + p[13]) + (p[14] + p[15]);
            lacc += (t0 + t1) + (t2 + t3);
        }

        // P^T B-frags via half-wave exchange; V^T A-frags loaded JIT from LDS
#pragma unroll
        for (int kc = 0; kc < 2; ++kc) {
            unsigned PA0 = pack_trunc(p[8 * kc + 0], p[8 * kc + 1]);
            unsigned PA1 = pack_trunc(p[8 * kc + 2], p[8 * kc + 3]);
            unsigned PB0 = pack_trunc(p[8 * kc + 4], p[8 * kc + 5]);
            unsigned PB1 = pack_trunc(p[8 * kc + 6], p[8 * kc + 7]);
            unsigned snd0 = half ? PA0 : PB0;
            unsigned snd1 = half ? PA1 : PB1;
            unsigned rcv0 = (unsigned)__shfl_xor((int)snd0, 32, 64);
            unsigned rcv1 = (unsigned)__shfl_xor((int)snd1, 32, 64);
            union { unsigned u[4]; bf16x8 v; } pf;
            pf.u[0] = half ? rcv0 : PA0;
            pf.u[1] = half ? rcv1 : PA1;
            pf.u[2] = half ? PB0 : rcv0;
            pf.u[3] = half ? PB1 : rcv1;
#pragma unroll
            for (int ds = 0; ds < 4; ++ds) {
                bf16x8 vfr = *(const bf16x8*)
                    &v_lds[(ds * 32 + l5) * 128 +
                           (((w * 4 + kc * 2 + half) ^ (l5 & 15)) * 8)];
                O[ds] = __builtin_amdgcn_mfma_f32_32x32x16_bf16(vfr, pf.v, O[ds], 0, 0, 0);
            }
        }
    }

    // l: partner half covers the other 16 keys of the wave's quarter
    lacc += __shfl_xor(lacc, 32, 64);
    __syncthreads();   // all K-loop LDS reads done; tiles now reusable as red_o
    if (half == 0) red_l[w * 32 + l5] = lacc;
#pragma unroll
    for (int ds = 0; ds < 4; ++ds)
#pragma unroll
        for (int r = 0; r < 16; ++r) {
            int d = ds * 32 + (r & 3) + 8 * (r >> 2) + 4 * half;
            red_o[w][l5][d] = O[ds][r];
        }
    __syncthreads();

    // combine 4 key-quarters, normalize, write bf16 (32B/thread coalesced)
    {
        int q = tid >> 3;
        int dg = tid & 7;
        float l = red_l[q] + red_l[32 + q] + red_l[64 + q] + red_l[96 + q];
        float inv = 1.f / l;
        unsigned outw[8];
#pragma unroll
        for (int i = 0; i < 8; ++i) {
            int d0 = dg * 16 + i * 2;
            float s0 = red_o[0][q][d0] + red_o[1][q][d0] +
                       red_o[2][q][d0] + red_o[3][q][d0];
            float s1 = red_o[0][q][d0 + 1] + red_o[1][q][d0 + 1] +
                       red_o[2][q][d0 + 1] + red_o[3][q][d0 + 1];
            outw[i] = pack2(s0 * inv, s1 * inv);
        }
        unsigned short* ob = of + (size_t)b * NN * DD + (size_t)(rw0 + q) * DD + dg * 16;
        *(uint4*)(ob) = *(uint4*)&outw[0];
        *(uint4*)(ob + 8) = *(uint4*)&outw[4];
    }
}

extern "C" void kernel_launch(void* const* d_in, const int* in_sizes, int n_in,
                              void* d_out, int out_size, void* d_ws, size_t ws_size,
                              hipStream_t stream) {
    const float* x_upper = (const float*)d_in[0];
    const float* x_lower = (const float*)d_in[1];
    const float* wq = (const float*)d_in[2];
    const float* bq = (const float*)d_in[3];
    const float* wk = (const float*)d_in[4];
    const float* bk = (const float*)d_in[5];
    const float* wv = (const float*)d_in[6];
    const float* bv = (const float*)d_in[7];
    const float* wo = (const float*)d_in[8];
    const float* bo = (const float*)d_in[9];
    float* out = (float*)d_out;

    const size_t ELT = (size_t)BB * NN * DD;        // 2M elements
    unsigned short* qf  = (unsigned short*)d_ws;    // [ 0, 4) MB
    unsigned short* kf  = qf + ELT;                 // [ 4, 8) MB
    unsigned short* vtb = kf + ELT;                 // [ 8,12) MB (d-major V)
    unsigned short* vfn = vtb + ELT;                // [12,16) MB (n-major V, temp)
    unsigned short* ofb = vfn + ELT;                // [16,20) MB (attn out bf16)
    // 20 MB total — proven footprint

    // Q pre-scaled by 1/sqrt(128) * log2(e): softmax is a bare v_exp_f32
    const float qscale = (float)(0.08838834764831845 * 1.4426950408889634);

    dim3 blk(256);
    proj_kernel<CIN><<<512, blk, 0, stream>>>(x_upper, wq, bq, qf, qscale);
    proj_kv_kernel<<<512, blk, 0, stream>>>(x_lower, wk, bk, wv, bv, kf, vfn);
    transpose_v<<<256, blk, 0, stream>>>(vfn, vtb);
    attn_mfma<<<BB * 128, blk, 0, stream>>>(qf, kf, vtb, ofb);
    proj_o_kernel<<<512, blk, 0, stream>>>(ofb, wo, bo, x_lower, out);
}

// Round 9
// 224.576 us; speedup vs baseline: 2.0345x; 2.0345x over previous
//
#include <hip/hip_runtime.h>
#include <math.h>

#define BB 4
#define CIN 64
#define CL 128     // 2*C_IN
#define DD 128     // projected dim
#define HW 4096
#define NN 4096
#define TP 132     // transpose lds pitch

typedef __attribute__((ext_vector_type(8))) __bf16 bf16x8;
typedef __attribute__((ext_vector_type(16))) float f32x16;

__device__ __forceinline__ unsigned short f2bf(float f) {
    unsigned u = __builtin_bit_cast(unsigned, f);
    u += 0x7fffu + ((u >> 16) & 1u);
    return (unsigned short)(u >> 16);
}
__device__ __forceinline__ unsigned pack2(float lo, float hi) {
    return (unsigned)f2bf(lo) | ((unsigned)f2bf(hi) << 16);
}
__device__ __forceinline__ float bf2f(unsigned s) {
    return __builtin_bit_cast(float, s << 16);
}
// truncating bf16 pair pack: 1 v_perm_b32 (P-operand only; bias <0.4%)
__device__ __forceinline__ unsigned pack_trunc(float lo, float hi) {
    return __builtin_amdgcn_perm(__builtin_bit_cast(unsigned, hi),
                                 __builtin_bit_cast(unsigned, lo), 0x07060302u);
}
__device__ __forceinline__ float exp2_fast(float x) {
#if __has_builtin(__builtin_amdgcn_exp2f)
    return __builtin_amdgcn_exp2f(x);
#else
    return __expf(x * 0.6931471805599453f);
#endif
}
// async global->LDS DMA, 16B/lane; LDS dst = wave-uniform base + lane*16
__device__ __forceinline__ void async_copy16(const unsigned short* g,
                                             unsigned short* l) {
    __builtin_amdgcn_global_load_lds(
        (const __attribute__((address_space(1))) void*)g,
        (__attribute__((address_space(3))) void*)l, 16, 0, 0);
}

// fp32-in projection, bf16 out, output scale. grid 512 = b*og(8)*chunk(16)
template<int CINT>
__global__ __launch_bounds__(256) void proj_kernel(
    const float* __restrict__ x, const float* __restrict__ w,
    const float* __restrict__ bias, unsigned short* __restrict__ out,
    float oscale)
{
    int blk = blockIdx.x;
    int chunk = blk & 15;
    int og = (blk >> 4) & 7;
    int b = blk >> 7;
    int o0 = og * 16;
    int hw = chunk * 256 + threadIdx.x;

    float acc[16];
#pragma unroll
    for (int oo = 0; oo < 16; ++oo) acc[oo] = bias[o0 + oo];
    const float* xb = x + (size_t)b * CINT * HW + hw;
    for (int c = 0; c < CINT; ++c) {
        float xv = xb[(size_t)c * HW];
#pragma unroll
        for (int oo = 0; oo < 16; ++oo)
            acc[oo] += xv * w[(o0 + oo) * CINT + c];
    }
#pragma unroll
    for (int oo = 0; oo < 16; ++oo)
        out[((size_t)b * 128 + o0 + oo) * HW + hw] = f2bf(acc[oo] * oscale);
}

// fused K+V projection. V: natural NCHW. K: DMA-ready swizzled layout —
// logical flat f=c*4096+hw -> n=f>>7, d=f&127, stored n*128+((d>>3)^(n&15))*8+(d&7)
__global__ __launch_bounds__(256) void proj_kv_kernel(
    const float* __restrict__ x,
    const float* __restrict__ wk, const float* __restrict__ bk,
    const float* __restrict__ wv, const float* __restrict__ bv,
    unsigned short* __restrict__ kout, unsigned short* __restrict__ vout)
{
    int blk = blockIdx.x;
    int chunk = blk & 15;
    int og = (blk >> 4) & 7;
    int b = blk >> 7;
    int o0 = og * 16;
    int hw = chunk * 256 + threadIdx.x;

    float ack[16], acv[16];
#pragma unroll
    for (int oo = 0; oo < 16; ++oo) { ack[oo] = bk[o0 + oo]; acv[oo] = bv[o0 + oo]; }
    const float* xb = x + (size_t)b * CL * HW + hw;
    for (int c = 0; c < CL; ++c) {
        float xv = xb[(size_t)c * HW];
#pragma unroll
        for (int oo = 0; oo < 16; ++oo) {
            ack[oo] += xv * wk[(o0 + oo) * CL + c];
            acv[oo] += xv * wv[(o0 + oo) * CL + c];
        }
    }
    int nlo = hw >> 7;                 // n = c*32 + nlo; n&15 == nlo&15
    int xs = (((hw >> 3) & 15) ^ (nlo & 15)) * 8 + (hw & 7);
    unsigned short* kb = kout + (size_t)b * NN * DD + (size_t)nlo * 128 + xs;
#pragma unroll
    for (int oo = 0; oo < 16; ++oo) {
        kb[(size_t)(o0 + oo) * 32 * 128] = f2bf(ack[oo]);
        size_t oidx = ((size_t)b * 128 + o0 + oo) * HW + hw;
        vout[oidx] = f2bf(acv[oo]);
    }
}

// output projection: bf16 in, fp32 out with residual. grid 512, 16 o x 256 px
__global__ __launch_bounds__(256) void proj_o_kernel(
    const unsigned short* __restrict__ x, const float* __restrict__ w,
    const float* __restrict__ bias, const float* __restrict__ resid,
    float* __restrict__ out)
{
    int blk = blockIdx.x;
    int chunk = blk & 15;
    int og = (blk >> 4) & 7;
    int b = blk >> 7;
    int o0 = og * 16;
    int hw = chunk * 256 + threadIdx.x;

    float acc[16];
#pragma unroll
    for (int oo = 0; oo < 16; ++oo) acc[oo] = bias[o0 + oo];
    const unsigned short* xb = x + (size_t)b * DD * HW + hw;
    for (int c = 0; c < DD; ++c) {
        float xv = bf2f((unsigned)xb[(size_t)c * HW]);
#pragma unroll
        for (int oo = 0; oo < 16; ++oo)
            acc[oo] += xv * w[(o0 + oo) * DD + c];
    }
#pragma unroll
    for (int oo = 0; oo < 16; ++oo) {
        size_t oidx = ((size_t)b * 128 + o0 + oo) * HW + hw;
        out[oidx] = acc[oo] + resid[oidx];
    }
}

// logical V[n][d] -> blocked DMA-ready V^T: [t][d][x^(d&15)][8], t=n>>7,
// x=(n&127)>>3, j=n&7; each tile = dense 32KB block
__global__ __launch_bounds__(256) void transpose_v(
    const unsigned short* __restrict__ vf, unsigned short* __restrict__ vt)
{
    __shared__ unsigned short tld[64 * TP];
    int tid = threadIdx.x;
    int b = blockIdx.x >> 6;
    int n0 = (blockIdx.x & 63) * 64;
    const unsigned short* src = vf + (size_t)b * NN * DD + (size_t)n0 * DD;
#pragma unroll
    for (int i = 0; i < 4; ++i) {
        int ch = tid + i * 256;
        int n = ch >> 4, x = ch & 15;
        union { uint4 q; unsigned long long u[2]; } t;
        t.q = *(const uint4*)(src + (size_t)n * DD + x * 8);
        unsigned short* d = &tld[n * TP + x * 8];
        *(unsigned long long*)(d) = t.u[0];
        *(unsigned long long*)(d + 4) = t.u[1];
    }
    __syncthreads();
    unsigned short* dst = vt + (size_t)b * NN * DD + (size_t)(n0 >> 7) * 16384;
    int xb_ = (n0 & 127) >> 3;         // base x-chunk of this block's 64 n
#pragma unroll
    for (int i = 0; i < 4; ++i) {
        int ch = tid + i * 256;
        int g = ch & 7, d = ch >> 3;
        union { uint4 q; unsigned short s[8]; } t;
#pragma unroll
        for (int j = 0; j < 8; ++j) t.s[j] = tld[(g * 8 + j) * TP + d];
        int xs = (xb_ + g) ^ (d & 15);
        *(uint4*)(dst + (size_t)d * 128 + xs * 8) = t.q;
    }
}

// MFMA flash attention v7: K/V staged by global_load_lds DMA (no VGPR staging,
// nothing to spill) into pre-swizzled dense tiles; S^T formulation,
// shfl-exchanged P, conflict-free b128 frag reads; epilogue LDS reduce.
__global__ __launch_bounds__(256, 2) void attn_mfma(
    const unsigned short* __restrict__ qf, const unsigned short* __restrict__ kfs,
    const unsigned short* __restrict__ vts, unsigned short* __restrict__ of)
{
    __shared__ __align__(16) char smem[73728];
    unsigned short* k_lds = (unsigned short*)smem;            // [128 key][16 x'][8]
    unsigned short* v_lds = (unsigned short*)(smem + 32768);  // [128 d][16 x'][8]
    unsigned short* q_lds = (unsigned short*)(smem + 65536);  // [32 q][16 x'][8]
    float (*red_o)[32][129] = (float (*)[32][129])smem;       // aliased after K-loop
    float* red_l = (float*)(smem + 66048);

    const int tid = threadIdx.x;
    const int lane = tid & 63;
    const int w = tid >> 6;            // wave 0..3 : key quarter
    const int half = lane >> 5;
    const int l5 = lane & 31;
    const int b = blockIdx.x >> 7;
    const int rw0 = (blockIdx.x & 127) * 32;   // block's 32 q-rows
    const int cw = w * 32;             // wave's key quarter in 128-supertile

    const unsigned short* qb = qf + (size_t)b * NN * DD;
    const unsigned short* kb = kfs + (size_t)b * NN * DD;   // pre-swizzled [n][128]
    const unsigned short* vb = vts + (size_t)b * NN * DD;   // blocked [t][d][128]

    // stage Q (32 x 128, swizzle applied here) once
#pragma unroll
    for (int j = 0; j < 2; ++j) {
        int ck = tid + j * 256;            // 512 chunks of 16B
        int qr = ck >> 4, qx = ck & 15;
        uint4 qv = *(const uint4*)(qb + (size_t)(rw0 + qr) * DD + qx * 8);
        *(uint4*)&q_lds[qr * 128 + ((qx ^ (qr & 15)) * 8)] = qv;
    }

    f32x16 O[4] = {};
    float lacc = 0.f;

    for (int t = 0; t < NN / 128; ++t) {
        __syncthreads();               // previous tile's frag reads done
        {   // DMA tile t: 32 KB K + 32 KB V, 1KB per call, 8+8 calls per wave
            const unsigned short* kt = kb + (size_t)t * 16384;
            const unsigned short* vt_ = vb + (size_t)t * 16384;
#pragma unroll
            for (int j = 0; j < 8; ++j) {
                int c = (w * 8 + j) * 512;
                async_copy16(kt + c + lane * 8, k_lds + c);
                async_copy16(vt_ + c + lane * 8, v_lds + c);
            }
        }
        __syncthreads();               // vmcnt drained -> tile visible

        // S^T = K·Q^T : A lane = key cw+l5; B lane = q-row l5 (deswizzled b128)
        f32x16 S = {};
#pragma unroll
        for (int kk = 0; kk < 8; ++kk) {
            bf16x8 kfr = *(const bf16x8*)
                &k_lds[(cw + l5) * 128 + (((kk * 2 + half) ^ (l5 & 15)) * 8)];
            bf16x8 qfr = *(const bf16x8*)
                &q_lds[l5 * 128 + (((kk * 2 + half) ^ (l5 & 15)) * 8)];
            S = __builtin_amdgcn_mfma_f32_32x32x16_bf16(kfr, qfr, S, 0, 0, 0);
        }

        // softmax numerator (no max subtraction: |S| < ~3 in log2 domain)
        float p[16];
#pragma unroll
        for (int r = 0; r < 16; ++r) p[r] = exp2_fast(S[r]);
        {
            float t0 = (p[0] + p[1]) + (p[2] + p[3]);
            float t1 = (p[4] + p[5]) + (p[6] + p[7]);
            float t2 = (p[8] + p[9]) + (p[10] + p[11]);
            float t3 = (p[12] + p[13]) + (p[14] + p[15]);
            lacc += (t0 + t1) + (t2 + t3);
        }

        // P^T B-frags via half-wave exchange; V^T A-frags JIT from LDS
#pragma unroll
        for (int kc = 0; kc < 2; ++kc) {
            unsigned PA0 = pack_trunc(p[8 * kc + 0], p[8 * kc + 1]);
            unsigned PA1 = pack_trunc(p[8 * kc + 2], p[8 * kc + 3]);
            unsigned PB0 = pack_trunc(p[8 * kc + 4], p[8 * kc + 5]);
            unsigned PB1 = pack_trunc(p[8 * kc + 6], p[8 * kc + 7]);
            unsigned snd0 = half ? PA0 : PB0;
            unsigned snd1 = half ? PA1 : PB1;
            unsigned rcv0 = (unsigned)__shfl_xor((int)snd0, 32, 64);
            unsigned rcv1 = (unsigned)__shfl_xor((int)snd1, 32, 64);
            union { unsigned u[4]; bf16x8 v; } pf;
            pf.u[0] = half ? rcv0 : PA0;
            pf.u[1] = half ? rcv1 : PA1;
            pf.u[2] = half ? PB0 : rcv0;
            pf.u[3] = half ? PB1 : rcv1;
#pragma unroll
            for (int ds = 0; ds < 4; ++ds) {
                bf16x8 vfr = *(const bf16x8*)
                    &v_lds[(ds * 32 + l5) * 128 +
                           (((w * 4 + kc * 2 + half) ^ (l5 & 15)) * 8)];
                O[ds] = __builtin_amdgcn_mfma_f32_32x32x16_bf16(vfr, pf.v, O[ds], 0, 0, 0);
            }
        }
    }

    // l: partner half covers the other 16 keys of the wave's quarter
    lacc += __shfl_xor(lacc, 32, 64);
    __syncthreads();   // all K-loop LDS reads done; tiles reusable as red_o
    if (half == 0) red_l[w * 32 + l5] = lacc;
#pragma unroll
    for (int ds = 0; ds < 4; ++ds)
#pragma unroll
        for (int r = 0; r < 16; ++r) {
            int d = ds * 32 + (r & 3) + 8 * (r >> 2) + 4 * half;
            red_o[w][l5][d] = O[ds][r];
        }
    __syncthreads();

    // combine 4 key-quarters, normalize, write bf16 (32B/thread coalesced)
    {
        int q = tid >> 3;
        int dg = tid & 7;
        float l = red_l[q] + red_l[32 + q] + red_l[64 + q] + red_l[96 + q];
        float inv = 1.f / l;
        unsigned outw[8];
#pragma unroll
        for (int i = 0; i < 8; ++i) {
            int d0 = dg * 16 + i * 2;
            float s0 = red_o[0][q][d0] + red_o[1][q][d0] +
                       red_o[2][q][d0] + red_o[3][q][d0];
            float s1 = red_o[0][q][d0 + 1] + red_o[1][q][d0 + 1] +
                       red_o[2][q][d0 + 1] + red_o[3][q][d0 + 1];
            outw[i] = pack2(s0 * inv, s1 * inv);
        }
        unsigned short* ob = of + (size_t)b * NN * DD + (size_t)(rw0 + q) * DD + dg * 16;
        *(uint4*)(ob) = *(uint4*)&outw[0];
        *(uint4*)(ob + 8) = *(uint4*)&outw[4];
    }
}

extern "C" void kernel_launch(void* const* d_in, const int* in_sizes, int n_in,
                              void* d_out, int out_size, void* d_ws, size_t ws_size,
                              hipStream_t stream) {
    const float* x_upper = (const float*)d_in[0];
    const float* x_lower = (const float*)d_in[1];
    const float* wq = (const float*)d_in[2];
    const float* bq = (const float*)d_in[3];
    const float* wk = (const float*)d_in[4];
    const float* bk = (const float*)d_in[5];
    const float* wv = (const float*)d_in[6];
    const float* bv = (const float*)d_in[7];
    const float* wo = (const float*)d_in[8];
    const float* bo = (const float*)d_in[9];
    float* out = (float*)d_out;

    const size_t ELT = (size_t)BB * NN * DD;        // 2M elements
    unsigned short* qf  = (unsigned short*)d_ws;    // [ 0, 4) MB natural
    unsigned short* kfs = qf + ELT;                 // [ 4, 8) MB swizzled
    unsigned short* vts = kfs + ELT;                // [ 8,12) MB blocked+swizzled
    unsigned short* vfn = vts + ELT;                // [12,16) MB natural V temp
    unsigned short* ofb = vfn + ELT;                // [16,20) MB attn out bf16
    // 20 MB total — proven footprint

    // Q pre-scaled by 1/sqrt(128) * log2(e): softmax is a bare v_exp_f32
    const float qscale = (float)(0.08838834764831845 * 1.4426950408889634);

    dim3 blk(256);
    proj_kernel<CIN><<<512, blk, 0, stream>>>(x_upper, wq, bq, qf, qscale);
    proj_kv_kernel<<<512, blk, 0, stream>>>(x_lower, wk, bk, wv, bv, kfs, vfn);
    transpose_v<<<256, blk, 0, stream>>>(vfn, vts);
    attn_mfma<<<BB * 128, blk, 0, stream>>>(qf, kfs, vts, ofb);
    proj_o_kernel<<<512, blk, 0, stream>>>(ofb, wo, bo, x_lower, out);
}

// Round 10
// 189.280 us; speedup vs baseline: 2.4138x; 1.1865x over previous
//
#include <hip/hip_runtime.h>
#include <math.h>

#define BB 4
#define CIN 64
#define CL 128     // 2*C_IN
#define DD 128     // projected dim
#define HW 4096
#define NN 4096
#define TP 132     // transpose lds pitch

typedef __attribute__((ext_vector_type(8))) __bf16 bf16x8;
typedef __attribute__((ext_vector_type(16))) float f32x16;

__device__ __forceinline__ unsigned short f2bf(float f) {
    unsigned u = __builtin_bit_cast(unsigned, f);
    u += 0x7fffu + ((u >> 16) & 1u);
    return (unsigned short)(u >> 16);
}
__device__ __forceinline__ unsigned pack2(float lo, float hi) {
    return (unsigned)f2bf(lo) | ((unsigned)f2bf(hi) << 16);
}
__device__ __forceinline__ float bf2f(unsigned s) {
    return __builtin_bit_cast(float, s << 16);
}
// truncating bf16 pair pack: 1 v_perm_b32 (P-operand only; bias <0.4%)
__device__ __forceinline__ unsigned pack_trunc(float lo, float hi) {
    return __builtin_amdgcn_perm(__builtin_bit_cast(unsigned, hi),
                                 __builtin_bit_cast(unsigned, lo), 0x07060302u);
}
__device__ __forceinline__ float exp2_fast(float x) {
#if __has_builtin(__builtin_amdgcn_exp2f)
    return __builtin_amdgcn_exp2f(x);
#else
    return __expf(x * 0.6931471805599453f);
#endif
}
// async global->LDS DMA, 16B/lane; LDS dst = wave-uniform base + lane*16
__device__ __forceinline__ void async_copy16(const unsigned short* g,
                                             unsigned short* l) {
    __builtin_amdgcn_global_load_lds(
        (const __attribute__((address_space(1))) void*)g,
        (__attribute__((address_space(3))) void*)l, 16, 0, 0);
}

// fp32-in q projection, bf16 out (natural NCHW), pre-scaled.
// grid 256 = b(4) x og(16: 8 outs) x chunk(4: 1024px); float4/thread.
__global__ __launch_bounds__(256) void proj_q_kernel(
    const float* __restrict__ x, const float* __restrict__ w,
    const float* __restrict__ bias, unsigned short* __restrict__ out,
    float oscale)
{
    int blk = blockIdx.x;
    int chunk = blk & 3;
    int og = (blk >> 2) & 15;
    int b = blk >> 6;
    int o0 = og * 8;
    int hw = chunk * 1024 + threadIdx.x * 4;

    float4 acc[8];
#pragma unroll
    for (int oo = 0; oo < 8; ++oo) {
        float bv = bias[o0 + oo];
        acc[oo] = make_float4(bv, bv, bv, bv);
    }
    const float* xb = x + (size_t)b * CIN * HW + hw;
#pragma unroll 4
    for (int c = 0; c < CIN; ++c) {
        float4 xv = *(const float4*)(xb + (size_t)c * HW);
#pragma unroll
        for (int oo = 0; oo < 8; ++oo) {
            float wv = w[(o0 + oo) * CIN + c];
            acc[oo].x += xv.x * wv; acc[oo].y += xv.y * wv;
            acc[oo].z += xv.z * wv; acc[oo].w += xv.w * wv;
        }
    }
#pragma unroll
    for (int oo = 0; oo < 8; ++oo) {
        size_t oidx = ((size_t)b * 128 + o0 + oo) * HW + hw;
        uint2 pv;
        pv.x = pack2(acc[oo].x * oscale, acc[oo].y * oscale);
        pv.y = pack2(acc[oo].z * oscale, acc[oo].w * oscale);
        *(uint2*)(out + oidx) = pv;
    }
}

// fused K+V projection (x_lower read once). K written in DMA-ready swizzled
// layout: elem (n,d) at n*128 + ((d>>3)^(n&15))*8 + (d&7), n=ch*32+(hw>>7),
// d=hw&127. V written natural NCHW (transpose_v consumes it).
// grid 256, 8 outs, float4/thread.
__global__ __launch_bounds__(256) void proj_kv_kernel(
    const float* __restrict__ x,
    const float* __restrict__ wk, const float* __restrict__ bk,
    const float* __restrict__ wv, const float* __restrict__ bv,
    unsigned short* __restrict__ kout, unsigned short* __restrict__ vout)
{
    int blk = blockIdx.x;
    int chunk = blk & 3;
    int og = (blk >> 2) & 15;
    int b = blk >> 6;
    int o0 = og * 8;
    int hw = chunk * 1024 + threadIdx.x * 4;

    float4 ack[8], acv[8];
#pragma unroll
    for (int oo = 0; oo < 8; ++oo) {
        float bkv = bk[o0 + oo], bvv = bv[o0 + oo];
        ack[oo] = make_float4(bkv, bkv, bkv, bkv);
        acv[oo] = make_float4(bvv, bvv, bvv, bvv);
    }
    const float* xb = x + (size_t)b * CL * HW + hw;
#pragma unroll 4
    for (int c = 0; c < CL; ++c) {
        float4 xv = *(const float4*)(xb + (size_t)c * HW);
#pragma unroll
        for (int oo = 0; oo < 8; ++oo) {
            float wkv = wk[(o0 + oo) * CL + c];
            float wvv = wv[(o0 + oo) * CL + c];
            ack[oo].x += xv.x * wkv; ack[oo].y += xv.y * wkv;
            ack[oo].z += xv.z * wkv; ack[oo].w += xv.w * wkv;
            acv[oo].x += xv.x * wvv; acv[oo].y += xv.y * wvv;
            acv[oo].z += xv.z * wvv; acv[oo].w += xv.w * wvv;
        }
    }
    int nlo = hw >> 7;                 // n = ch*32 + nlo; n&15 == nlo&15
    int xs = (((hw >> 3) & 15) ^ (nlo & 15)) * 8 + (hw & 7);  // 8B-aligned
    unsigned short* kb = kout + (size_t)b * NN * DD + (size_t)nlo * 128 + xs;
#pragma unroll
    for (int oo = 0; oo < 8; ++oo) {
        uint2 kv2, vv2;
        kv2.x = pack2(ack[oo].x, ack[oo].y);
        kv2.y = pack2(ack[oo].z, ack[oo].w);
        vv2.x = pack2(acv[oo].x, acv[oo].y);
        vv2.y = pack2(acv[oo].z, acv[oo].w);
        *(uint2*)(kb + (size_t)(o0 + oo) * 32 * 128) = kv2;
        size_t oidx = ((size_t)b * 128 + o0 + oo) * HW + hw;
        *(uint2*)(vout + oidx) = vv2;
    }
}

// output projection: bf16 in (ofb), fp32 out with residual.
// grid 256, 8 outs, 4 px/thread.
__global__ __launch_bounds__(256) void proj_o_kernel(
    const unsigned short* __restrict__ x, const float* __restrict__ w,
    const float* __restrict__ bias, const float* __restrict__ resid,
    float* __restrict__ out)
{
    int blk = blockIdx.x;
    int chunk = blk & 3;
    int og = (blk >> 2) & 15;
    int b = blk >> 6;
    int o0 = og * 8;
    int hw = chunk * 1024 + threadIdx.x * 4;

    float4 acc[8];
#pragma unroll
    for (int oo = 0; oo < 8; ++oo) {
        float bv = bias[o0 + oo];
        acc[oo] = make_float4(bv, bv, bv, bv);
    }
    const unsigned short* xb = x + (size_t)b * DD * HW + hw;
#pragma unroll 4
    for (int c = 0; c < DD; ++c) {
        uint2 xr = *(const uint2*)(xb + (size_t)c * HW);
        float x0 = bf2f(xr.x & 0xffffu), x1 = bf2f(xr.x >> 16);
        float x2 = bf2f(xr.y & 0xffffu), x3 = bf2f(xr.y >> 16);
#pragma unroll
        for (int oo = 0; oo < 8; ++oo) {
            float wv = w[(o0 + oo) * DD + c];
            acc[oo].x += x0 * wv; acc[oo].y += x1 * wv;
            acc[oo].z += x2 * wv; acc[oo].w += x3 * wv;
        }
    }
#pragma unroll
    for (int oo = 0; oo < 8; ++oo) {
        size_t oidx = ((size_t)b * 128 + o0 + oo) * HW + hw;
        float4 rv = *(const float4*)(resid + oidx);
        acc[oo].x += rv.x; acc[oo].y += rv.y;
        acc[oo].z += rv.z; acc[oo].w += rv.w;
        *(float4*)(out + oidx) = acc[oo];
    }
}

// logical V[n][d] -> blocked DMA-ready V^T: [t][d][x^(d&15)][8], t=n>>7,
// x=(n&127)>>3, j=n&7; each tile = dense 32KB block
__global__ __launch_bounds__(256) void transpose_v(
    const unsigned short* __restrict__ vf, unsigned short* __restrict__ vt)
{
    __shared__ unsigned short tld[64 * TP];
    int tid = threadIdx.x;
    int b = blockIdx.x >> 6;
    int n0 = (blockIdx.x & 63) * 64;
    const unsigned short* src = vf + (size_t)b * NN * DD + (size_t)n0 * DD;
#pragma unroll
    for (int i = 0; i < 4; ++i) {
        int ch = tid + i * 256;
        int n = ch >> 4, x = ch & 15;
        union { uint4 q; unsigned long long u[2]; } t;
        t.q = *(const uint4*)(src + (size_t)n * DD + x * 8);
        unsigned short* d = &tld[n * TP + x * 8];
        *(unsigned long long*)(d) = t.u[0];
        *(unsigned long long*)(d + 4) = t.u[1];
    }
    __syncthreads();
    unsigned short* dst = vt + (size_t)b * NN * DD + (size_t)(n0 >> 7) * 16384;
    int xb_ = (n0 & 127) >> 3;         // base x-chunk of this block's 64 n
#pragma unroll
    for (int i = 0; i < 4; ++i) {
        int ch = tid + i * 256;
        int g = ch & 7, d = ch >> 3;
        union { uint4 q; unsigned short s[8]; } t;
#pragma unroll
        for (int j = 0; j < 8; ++j) t.s[j] = tld[(g * 8 + j) * TP + d];
        int xs = (xb_ + g) ^ (d & 15);
        *(uint4*)(dst + (size_t)d * 128 + xs * 8) = t.q;
    }
}

// MFMA flash attention v8: K/V staged by global_load_lds DMA into pre-swizzled
// dense tiles; Q frags in VGPRs (one-time divergent load, R4-proven);
// S^T formulation, shfl-exchanged P, conflict-free b128 frag reads.
__global__ __launch_bounds__(256, 2) void attn_mfma(
    const unsigned short* __restrict__ qf, const unsigned short* __restrict__ kfs,
    const unsigned short* __restrict__ vts, unsigned short* __restrict__ of)
{
    __shared__ __align__(16) char smem[66560];
    unsigned short* k_lds = (unsigned short*)smem;            // [128 key][16 x'][8]
    unsigned short* v_lds = (unsigned short*)(smem + 32768);  // [128 d][16 x'][8]
    float (*red_o)[32][129] = (float (*)[32][129])smem;       // aliased after K-loop
    float* red_l = (float*)(smem + 66048);

    const int tid = threadIdx.x;
    const int lane = tid & 63;
    const int w = tid >> 6;            // wave 0..3 : key quarter
    const int half = lane >> 5;
    const int l5 = lane & 31;
    const int b = blockIdx.x >> 7;
    const int rw0 = (blockIdx.x & 127) * 32;   // block's 32 q-rows
    const int cw = w * 32;             // wave's key quarter in 128-supertile

    const unsigned short* qb = qf + (size_t)b * NN * DD;
    const unsigned short* kb = kfs + (size_t)b * NN * DD;   // pre-swizzled [n][128]
    const unsigned short* vb = vts + (size_t)b * NN * DD;   // blocked [t][d][128]

    // Q as B-frag in VGPRs: lane l5 = q-row, k = kk*16 + half*8 + j
    bf16x8 qfrag[8];
    {
        const unsigned short* qrow = qb + (size_t)(rw0 + l5) * DD + half * 8;
#pragma unroll
        for (int kk = 0; kk < 8; ++kk)
            qfrag[kk] = *(const bf16x8*)(qrow + kk * 16);
    }

    f32x16 O[4] = {};
    float lacc = 0.f;

    for (int t = 0; t < NN / 128; ++t) {
        __syncthreads();               // previous tile's frag reads done
        {   // DMA tile t: 32 KB K + 32 KB V, 1KB per call, 8+8 calls per wave
            const unsigned short* kt = kb + (size_t)t * 16384;
            const unsigned short* vt_ = vb + (size_t)t * 16384;
#pragma unroll
            for (int j = 0; j < 8; ++j) {
                int c = (w * 8 + j) * 512;
                async_copy16(kt + c + lane * 8, k_lds + c);
                async_copy16(vt_ + c + lane * 8, v_lds + c);
            }
        }
        __syncthreads();               // vmcnt drained -> tile visible

        // S^T = K·Q^T : A lane = key cw+l5 (deswizzled b128)
        f32x16 S = {};
#pragma unroll
        for (int kk = 0; kk < 8; ++kk) {
            bf16x8 kfr = *(const bf16x8*)
                &k_lds[(cw + l5) * 128 + (((kk * 2 + half) ^ (l5 & 15)) * 8)];
            S = __builtin_amdgcn_mfma_f32_32x32x16_bf16(kfr, qfrag[kk], S, 0, 0, 0);
        }

        // softmax numerator (no max subtraction: |S| < ~3 in log2 domain)
        float p[16];
#pragma unroll
        for (int r = 0; r < 16; ++r) p[r] = exp2_fast(S[r]);
        {
            float t0 = (p[0] + p[1]) + (p[2] + p[3]);
            float t1 = (p[4] + p[5]) + (p[6] + p[7]);
            float t2 = (p[8] + p[9]) + (p[10] + p[11]);
            float t3 = (p[12] + p[13]) + (p[14] + p[15]);
            lacc += (t0 + t1) + (t2 + t3);
        }

        // P^T B-frags via half-wave exchange; V^T A-frags JIT from LDS
#pragma unroll
        for (int kc = 0; kc < 2; ++kc) {
            unsigned PA0 = pack_trunc(p[8 * kc + 0], p[8 * kc + 1]);
            unsigned PA1 = pack_trunc(p[8 * kc + 2], p[8 * kc + 3]);
            unsigned PB0 = pack_trunc(p[8 * kc + 4], p[8 * kc + 5]);
            unsigned PB1 = pack_trunc(p[8 * kc + 6], p[8 * kc + 7]);
            unsigned snd0 = half ? PA0 : PB0;
            unsigned snd1 = half ? PA1 : PB1;
            unsigned rcv0 = (unsigned)__shfl_xor((int)snd0, 32, 64);
            unsigned rcv1 = (unsigned)__shfl_xor((int)snd1, 32, 64);
            union { unsigned u[4]; bf16x8 v; } pf;
            pf.u[0] = half ? rcv0 : PA0;
            pf.u[1] = half ? rcv1 : PA1;
            pf.u[2] = half ? PB0 : rcv0;
            pf.u[3] = half ? PB1 : rcv1;
#pragma unroll
            for (int ds = 0; ds < 4; ++ds) {
                bf16x8 vfr = *(const bf16x8*)
                    &v_lds[(ds * 32 + l5) * 128 +
                           (((w * 4 + kc * 2 + half) ^ (l5 & 15)) * 8)];
                O[ds] = __builtin_amdgcn_mfma_f32_32x32x16_bf16(vfr, pf.v, O[ds], 0, 0, 0);
            }
        }
    }

    // l: partner half covers the other 16 keys of the wave's quarter
    lacc += __shfl_xor(lacc, 32, 64);
    __syncthreads();   // all K-loop LDS reads done; tiles reusable as red_o
    if (half == 0) red_l[w * 32 + l5] = lacc;
#pragma unroll
    for (int ds = 0; ds < 4; ++ds)
#pragma unroll
        for (int r = 0; r < 16; ++r) {
            int d = ds * 32 + (r & 3) + 8 * (r >> 2) + 4 * half;
            red_o[w][l5][d] = O[ds][r];
        }
    __syncthreads();

    // combine 4 key-quarters, normalize, write bf16 (32B/thread coalesced)
    {
        int q = tid >> 3;
        int dg = tid & 7;
        float l = red_l[q] + red_l[32 + q] + red_l[64 + q] + red_l[96 + q];
        float inv = 1.f / l;
        unsigned outw[8];
#pragma unroll
        for (int i = 0; i < 8; ++i) {
            int d0 = dg * 16 + i * 2;
            float s0 = red_o[0][q][d0] + red_o[1][q][d0] +
                       red_o[2][q][d0] + red_o[3][q][d0];
            float s1 = red_o[0][q][d0 + 1] + red_o[1][q][d0 + 1] +
                       red_o[2][q][d0 + 1] + red_o[3][q][d0 + 1];
            outw[i] = pack2(s0 * inv, s1 * inv);
        }
        unsigned short* ob = of + (size_t)b * NN * DD + (size_t)(rw0 + q) * DD + dg * 16;
        *(uint4*)(ob) = *(uint4*)&outw[0];
        *(uint4*)(ob + 8) = *(uint4*)&outw[4];
    }
}

extern "C" void kernel_launch(void* const* d_in, const int* in_sizes, int n_in,
                              void* d_out, int out_size, void* d_ws, size_t ws_size,
                              hipStream_t stream) {
    const float* x_upper = (const float*)d_in[0];
    const float* x_lower = (const float*)d_in[1];
    const float* wq = (const float*)d_in[2];
    const float* bq = (const float*)d_in[3];
    const float* wk = (const float*)d_in[4];
    const float* bk = (const float*)d_in[5];
    const float* wv = (const float*)d_in[6];
    const float* bv = (const float*)d_in[7];
    const float* wo = (const float*)d_in[8];
    const float* bo = (const float*)d_in[9];
    float* out = (float*)d_out;

    const size_t ELT = (size_t)BB * NN * DD;        // 2M elements
    unsigned short* qf  = (unsigned short*)d_ws;    // [ 0, 4) MB natural
    unsigned short* kfs = qf + ELT;                 // [ 4, 8) MB swizzled
    unsigned short* vts = kfs + ELT;                // [ 8,12) MB blocked+swizzled
    unsigned short* vfn = vts + ELT;                // [12,16) MB natural V temp
    unsigned short* ofb = vfn + ELT;                // [16,20) MB attn out bf16
    // 20 MB total — proven footprint

    // Q pre-scaled by 1/sqrt(128) * log2(e): softmax is a bare v_exp_f32
    const float qscale = (float)(0.08838834764831845 * 1.4426950408889634);

    dim3 blk(256);
    proj_q_kernel<<<256, blk, 0, stream>>>(x_upper, wq, bq, qf, qscale);
    proj_kv_kernel<<<256, blk, 0, stream>>>(x_lower, wk, bk, wv, bv, kfs, vfn);
    transpose_v<<<256, blk, 0, stream>>>(vfn, vts);
    attn_mfma<<<BB * 128, blk, 0, stream>>>(qf, kfs, vts, ofb);
    proj_o_kernel<<<256, blk, 0, stream>>>(ofb, wo, bo, x_lower, out);
}